// Round 4
// baseline (223.546 us; speedup 1.0000x reference)
//
#include <hip/hip_runtime.h>
#include <stdint.h>
#include <math.h>

#define TPB 1024
#define NB 2048           // histogram bins (k2 phase)
#define SPLIT 4           // row split for scan blocks
#define LCAND 2560        // per-quarter-row candidate cap
#define CAND2 2048        // candidate cap in k2 phase
#define PS 4096           // presample count per block (== 4*TPB for vector path)
#define L2E 1.44269504088896f

typedef float vfloat4 __attribute__((ext_vector_type(4)));
typedef unsigned long long ull;

// monotonic float -> uint key (ascending key == ascending float)
__device__ __forceinline__ unsigned fkey(float f) {
    unsigned u = __float_as_uint(f);
    return (u & 0x80000000u) ? ~u : (u | 0x80000000u);
}
__device__ __forceinline__ float funkey(unsigned k) {
    unsigned u = (k & 0x80000000u) ? (k ^ 0x80000000u) : ~k;
    return __uint_as_float(u);
}
__device__ __forceinline__ ull packkv(unsigned k, unsigned idx) {
    return ((ull)k << 32) | (ull)(~idx);    // ~idx: desc key sort => asc idx ties
}

// Phi^{-1}(1-p) for 1e-7 <= p <= 0.45 (Hastings / A&S 26.2.23, |err|<4.5e-4)
__device__ __forceinline__ float inv_norm_tail(float p) {
    float t = sqrtf(-2.0f * logf(p));
    float num = 2.515517f + t * (0.802853f + t * 0.010328f);
    float den = 1.0f + t * (1.432788f + t * (0.189269f + t * 0.001308f));
    return t - num / den;
}

// in-place suffix sum of h[0..NB). Caller must barrier before; ends barriered.
__device__ __forceinline__ void suffix_scan_2048(unsigned* h, unsigned* wscr, int tid)
{
    const int lane = tid & 63, w = tid >> 6;
    const int i0 = 2047 - 2 * tid;
    const int i1 = 2046 - 2 * tid;
    unsigned a = h[i0], b = h[i1];
    unsigned s = a + b;
    unsigned inc = s;
    #pragma unroll
    for (int d = 1; d < 64; d <<= 1) { unsigned o = __shfl_up(inc, d); if (lane >= d) inc += o; }
    if (lane == 63) wscr[w] = inc;
    __syncthreads();
    if (w == 0) {
        unsigned v = (lane < 16) ? wscr[lane] : 0u;
        unsigned vi = v;
        #pragma unroll
        for (int d = 1; d < 16; d <<= 1) { unsigned o = __shfl_up(vi, d); if (lane >= d) vi += o; }
        if (lane < 16) wscr[16 + lane] = vi - v;
    }
    __syncthreads();
    unsigned off = wscr[16 + w] + (inc - s);
    h[i0] = off + a;
    h[i1] = off + a + b;
    __syncthreads();
}

// ============================ FUSED ============================
// grid = SPLIT*B. Phase 1 (all blocks): per-quarter scan exactly as before
// (moment cut -> zero epilogue -> streaming Z/gather/max). Then per-row
// completion counter: the LAST finisher of each row acquires the other
// quarters' data (device-scope fence) and runs the sampling phase in-place.
// Sampling for early rows overlaps streaming of late rows; one launch saved.
__global__ __launch_bounds__(TPB)
void k_fused(const float* __restrict__ logits,
             const float* __restrict__ temps,
             const int* __restrict__ top_ks,
             const float* __restrict__ top_ps,
             const float* __restrict__ min_ps,
             const float* __restrict__ uvec,
             float* __restrict__ out_tok,
             float* __restrict__ out_probs,
             float* __restrict__ ws_meta,   // [slot][2] {Cy, z}
             unsigned* __restrict__ ws_cut, // [slot]
             unsigned* __restrict__ ws_cnt, // [slot] raw count (overflow visible)
             unsigned* __restrict__ ws_max, // [slot] fkey(full-quarter max)
             ull* __restrict__ ws_cand,     // [slot][LCAND]
             unsigned* __restrict__ ws_done,// [B] zeroed by host-side memset
             int V, int Vq)
{
    const int sblk = blockIdx.x;
    const int b = sblk / SPLIT, s = sblk % SPLIT;
    const int tid = threadIdx.x, lane = tid & 63, w = tid >> 6;
    const int start = s * Vq;
    const int len = min(Vq, V - start);
    const int slot = sblk;
    const float invT = 1.0f / temps[b];
    int K = top_ks[b]; K = max(K, 1); K = min(K, 1024);

    // -------- shared --------
    __shared__ __align__(16) char smem[53504];   // k2-phase carve
    ull*            cand  = (ull*)(smem);                       // [2048] (fb path)
    ull*            cand2 = (ull*)(smem + 16384);               // [2048] sorted dest
    unsigned*       hist  = (unsigned*)(smem + 32768);          // [2049]
    unsigned short* cnts  = (unsigned short*)(smem + 41216);    // [2048]
    float*          sh_p  = (float*)(smem + 45312);             // [1024]
    float*          sh_c  = (float*)(smem + 49408);             // [1024]
    __shared__ float fred[52];     // phase1: sums/max scratch + results
    __shared__ unsigned uscr[32];
    __shared__ float fws[32];
    __shared__ unsigned cnt, scnt, sh_last;
    __shared__ int sh_i1, sh_i2;
    __shared__ unsigned sh_u1;

    // ==================== PHASE 1: quarter scan ====================
    if (len <= 0) {
        if (tid == 0) {
            ws_meta[2*slot] = -1e30f; ws_meta[2*slot+1] = 0.0f;
            ws_cut[slot] = 0xFFFFFFFFu; ws_cnt[slot] = 0u; ws_max[slot] = 0u;
        }
    } else {
        if (tid == 0) cnt = 0;

        const float* __restrict__ row = logits + (size_t)b * V + start;
        const vfloat4* __restrict__ row4 = (const vfloat4*)row;
        float* __restrict__ orow = out_probs + (size_t)b * V + start;
        vfloat4* __restrict__ orow4 = (vfloat4*)orow;
        const vfloat4 z4 = (vfloat4)0.0f;
        const int L4 = len >> 2;
        const bool vec = (len >= 4 * TPB);     // presample fits 1 float4/thread
        const int nps = vec ? (4 * TPB) : min(len, PS);

        // ---- presample: sum/sumsq/max; vector path keeps values in regs ----
        float sm = 0.0f, sq = 0.0f, m0 = -1e30f;
        vfloat4 pv = z4;
        if (vec) {
            pv = row4[tid];
            __builtin_nontemporal_store(z4, &orow4[tid]);   // zero presample region
            sm = (pv[0] + pv[1]) + (pv[2] + pv[3]);
            sq = (pv[0]*pv[0] + pv[1]*pv[1]) + (pv[2]*pv[2] + pv[3]*pv[3]);
            m0 = fmaxf(fmaxf(pv[0], pv[1]), fmaxf(pv[2], pv[3]));
        } else {
            for (int i = tid; i < nps; i += TPB) {
                float lv = row[i];
                sm += lv; sq += lv * lv;
                m0 = fmaxf(m0, lv);
            }
        }
        #pragma unroll
        for (int d = 32; d > 0; d >>= 1) {
            sm += __shfl_down(sm, d);
            sq += __shfl_down(sq, d);
            m0 = fmaxf(m0, __shfl_down(m0, d));
        }
        if (lane == 0) { fred[w] = sm; fred[16 + w] = sq; fred[32 + w] = m0; }
        __syncthreads();
        if (tid == 0) {
            float S = 0.0f, Q = 0.0f, M = -1e30f;
            for (int j = 0; j < 16; ++j) {
                S += fred[j]; Q += fred[16 + j]; M = fmaxf(M, fred[32 + j]);
            }
            float n  = (float)nps;
            float mu = S / n;
            float var = fmaxf(Q / n - mu * mu, 0.0f);
            float sg = sqrtf(var);
            float Cf = 2.0f * (float)K + 256.0f;          // target row survivors
            float p  = Cf / (float)V;
            p = fminf(fmaxf(p, 1e-7f), 0.45f);
            fred[48] = mu + sg * inv_norm_tail(p);        // cutval
            fred[49] = M;                                 // exp base (sample max)
        }
        __syncthreads();
        const float cutval = fred[48];
        const float m0max  = fred[49];
        const unsigned cutkey = fkey(cutval);

        // ---- zero epilogue FIRST (nt stores drain while reads stream) ----
        if (vec) {
            for (int i = TPB + tid; i < L4; i += TPB) __builtin_nontemporal_store(z4, &orow4[i]);
            for (int i = (L4 << 2) + tid; i < len; i += TPB) __builtin_nontemporal_store(0.0f, &orow[i]);
        } else {
            for (int i = tid; i < L4; i += TPB) __builtin_nontemporal_store(z4, &orow4[i]);
            for (int i = (L4 << 2) + tid; i < len; i += TPB) __builtin_nontemporal_store(0.0f, &orow[i]);
        }

        const float ca = invT * L2E;
        const float cb = -m0max * invT * L2E;
        ull* gc = ws_cand + (size_t)slot * LCAND;

        float z0 = 0.0f, z1 = 0.0f, z2 = 0.0f, z3 = 0.0f;
        float mA = m0, mB = -1e30f, mC = -1e30f, mD = -1e30f;

        #define E4(v) (exp2f(fmaf((v)[0], ca, cb)) + exp2f(fmaf((v)[1], ca, cb)) \
                     + exp2f(fmaf((v)[2], ca, cb)) + exp2f(fmaf((v)[3], ca, cb)))
        #define M4(v) fmaxf(fmaxf((v)[0], (v)[1]), fmaxf((v)[2], (v)[3]))
        #define GATHER(v, ii) do {                                                  \
            bool c0 = (v)[0] >= cutval, c1 = (v)[1] >= cutval,                      \
                 c2 = (v)[2] >= cutval, c3 = (v)[3] >= cutval;                      \
            if (c0 | c1 | c2 | c3) {                                                \
                int nh = (int)c0 + (int)c1 + (int)c2 + (int)c3;                     \
                unsigned base = atomicAdd(&cnt, (unsigned)nh);                      \
                unsigned bi = (unsigned)(start + ((ii) << 2));                      \
                if (c0) { if (base < LCAND) gc[base] = packkv(fkey((v)[0]), bi+0); base++; } \
                if (c1) { if (base < LCAND) gc[base] = packkv(fkey((v)[1]), bi+1); base++; } \
                if (c2) { if (base < LCAND) gc[base] = packkv(fkey((v)[2]), bi+2); base++; } \
                if (c3) { if (base < LCAND) gc[base] = packkv(fkey((v)[3]), bi+3); base++; } \
            }                                                                       \
        } while (0)

        // ---- main read pass: 4 plain loads in flight, 4 indep accumulators ----
        if (vec) {
            int i = TPB + tid;
            for (; i + 3 * TPB < L4; i += 4 * TPB) {
                vfloat4 va = row4[i];
                vfloat4 vb = row4[i + TPB];
                vfloat4 vc = row4[i + 2 * TPB];
                vfloat4 vd = row4[i + 3 * TPB];
                z0 += E4(va); z1 += E4(vb); z2 += E4(vc); z3 += E4(vd);
                mA = fmaxf(mA, M4(va)); mB = fmaxf(mB, M4(vb));
                mC = fmaxf(mC, M4(vc)); mD = fmaxf(mD, M4(vd));
                GATHER(va, i); GATHER(vb, i + TPB); GATHER(vc, i + 2 * TPB); GATHER(vd, i + 3 * TPB);
            }
            for (; i < L4; i += TPB) {
                vfloat4 v = row4[i];
                z0 += E4(v);
                mA = fmaxf(mA, M4(v));
                GATHER(v, i);
            }
            for (int j = (L4 << 2) + tid; j < len; j += TPB) {
                float lv = row[j];
                z0 += exp2f(fmaf(lv, ca, cb));
                mA = fmaxf(mA, lv);
                if (lv >= cutval) {
                    unsigned base = atomicAdd(&cnt, 1u);
                    if (base < LCAND) gc[base] = packkv(fkey(lv), (unsigned)(start + j));
                }
            }
            // presample values (already loaded, already zero-stored)
            z0 += E4(pv);
            GATHER(pv, tid);
        } else {
            int i = tid;
            for (; i + 3 * TPB < L4; i += 4 * TPB) {
                vfloat4 va = row4[i];
                vfloat4 vb = row4[i + TPB];
                vfloat4 vc = row4[i + 2 * TPB];
                vfloat4 vd = row4[i + 3 * TPB];
                z0 += E4(va); z1 += E4(vb); z2 += E4(vc); z3 += E4(vd);
                mA = fmaxf(mA, M4(va)); mB = fmaxf(mB, M4(vb));
                mC = fmaxf(mC, M4(vc)); mD = fmaxf(mD, M4(vd));
                GATHER(va, i); GATHER(vb, i + TPB); GATHER(vc, i + 2 * TPB); GATHER(vd, i + 3 * TPB);
            }
            for (; i < L4; i += TPB) {
                vfloat4 v = row4[i];
                z0 += E4(v);
                mA = fmaxf(mA, M4(v));
                GATHER(v, i);
            }
            for (int j = (L4 << 2) + tid; j < len; j += TPB) {
                float lv = row[j];
                z0 += exp2f(fmaf(lv, ca, cb));
                mA = fmaxf(mA, lv);
                if (lv >= cutval) {
                    unsigned base = atomicAdd(&cnt, 1u);
                    if (base < LCAND) gc[base] = packkv(fkey(lv), (unsigned)(start + j));
                }
            }
        }
        #undef E4
        #undef M4
        #undef GATHER

        float z = (z0 + z1) + (z2 + z3);
        unsigned rk = fkey(fmaxf(fmaxf(mA, mB), fmaxf(mC, mD)));
        __syncthreads();   // drains all threads' global stores; protects fred/uscr
        #pragma unroll
        for (int d = 32; d > 0; d >>= 1) {
            z += __shfl_down(z, d);
            rk = max(rk, __shfl_down(rk, d));
        }
        if (lane == 0) { fred[w] = z; uscr[w] = rk; }
        __syncthreads();
        if (tid == 0) {
            float zz = 0.0f;
            unsigned mk = 0u;
            for (int j = 0; j < 16; ++j) { zz += fred[j]; mk = max(mk, uscr[j]); }
            ws_meta[2*slot + 0] = m0max * invT;   // Cy
            ws_meta[2*slot + 1] = zz;             // sum 2^((x-m0max)*invT*L2E)
            ws_cut[slot] = cutkey;
            ws_cnt[slot] = cnt;
            ws_max[slot] = mk;
        }
    }

    // ==================== JOIN: last finisher runs sampling ====================
    if (tid == 0) {
        __threadfence();                              // release: publish quarter data
        unsigned old = atomicAdd(&ws_done[b], 1u);    // device-scope
        sh_last = (old == (unsigned)(SPLIT - 1)) ? 1u : 0u;
    }
    __syncthreads();
    if (!sh_last) return;
    __threadfence();                                  // acquire: see other quarters

    // ==================== PHASE 2: sampling for row b ====================
    {
        const int Korig = K;
        const unsigned Ku = (unsigned)Korig;
        const float top_p = top_ps[b], min_p = min_ps[b], uval = uvec[b];

        // ---- combine per-block meta ----
        float Cy[SPLIT], zq[SPLIT];
        unsigned cutq[SPLIT], cntq[SPLIT], mxq[SPLIT];
        #pragma unroll
        for (int q = 0; q < SPLIT; ++q) {
            int sl = b * SPLIT + q;
            Cy[q] = ws_meta[2*sl]; zq[q] = ws_meta[2*sl+1];
            cutq[q] = ws_cut[sl]; cntq[q] = ws_cnt[sl]; mxq[q] = ws_max[sl];
        }
        float Y = -1e30f;
        #pragma unroll
        for (int q = 0; q < SPLIT; ++q) if (cntq[q] > 0u) Y = fmaxf(Y, Cy[q]);
        float Z = 0.0f;
        #pragma unroll
        for (int q = 0; q < SPLIT; ++q)
            if (cntq[q] > 0u && zq[q] > 0.0f) Z += zq[q] * exp2f((Cy[q] - Y) * L2E);

        bool fb = false;
        unsigned cutmax = 0, mincut = 0xFFFFFFFFu;
        #pragma unroll
        for (int q = 0; q < SPLIT; ++q) {
            if (cntq[q] > (unsigned)LCAND) fb = true;          // list truncated
            if (cntq[q] > 0u) {
                if (!isfinite(zq[q])) fb = true;               // Z overflow -> exact path
                cutmax = max(cutmax, cutq[q]);
                mincut = min(mincut, cutq[q]);
            }
        }
        if (mincut == 0xFFFFFFFFu || !isfinite(Z) || Z <= 0.0f) fb = true;

        unsigned Tkeyb = 0;
        int count = 0, bstar = 0, shift = 0;
        unsigned base = mincut;

        // ---------- fast path: one adaptive histogram over candidate lists ----------
        if (!fb) {
            for (int i = tid; i <= NB; i += TPB) hist[i] = 0;   // incl hist[2048]
            if (tid == 0) sh_i1 = -1;
            unsigned maxkey = 0;
            #pragma unroll
            for (int q = 0; q < SPLIT; ++q)
                if (cntq[q] > 0u) maxkey = max(maxkey, mxq[q]);
            const unsigned range = maxkey - base;
            while ((range >> shift) > (unsigned)(NB - 1)) shift++;
            __syncthreads();

            // histogram pass
            #pragma unroll
            for (int q = 0; q < SPLIT; ++q) {
                const ull* gc = ws_cand + (size_t)(b * SPLIT + q) * LCAND;
                int nl = min((int)cntq[q], LCAND);
                for (int i = tid; i < nl; i += TPB)
                    atomicAdd(&hist[((unsigned)(gc[i] >> 32) - base) >> shift], 1u);
            }
            __syncthreads();
            unsigned fat = 0;
            for (int i = tid; i < NB; i += TPB) {
                unsigned h = hist[i];
                cnts[i] = (unsigned short)h;
                fat = max(fat, h);
            }
            #pragma unroll
            for (int d = 32; d > 0; d >>= 1) fat = max(fat, __shfl_down(fat, d));
            if (lane == 0) uscr[w] = fat;
            __syncthreads();
            if (tid == 0) {
                unsigned m2 = 0;
                for (int j = 0; j < 16; ++j) m2 = max(m2, uscr[j]);
                uscr[16] = m2;
            }
            __syncthreads();
            if (uscr[16] > 64u) fb = true;                      // fat bin -> fallback
        }
        if (!fb) {
            suffix_scan_2048(hist, uscr, tid);
            for (int e = tid; e < NB; e += TPB) {
                unsigned Se = hist[e], Sn = (e < NB - 1) ? hist[e + 1] : 0u;
                if (Se >= Ku && Sn < Ku) { sh_i1 = e; sh_u1 = Se; }
            }
            __syncthreads();
            if (sh_i1 < 0) fb = true;
            else {
                bstar = sh_i1;
                count = (int)sh_u1;
                Tkeyb = base + ((unsigned)bstar << shift);
                if (Tkeyb < cutmax || count > CAND2) fb = true; // exactness guards
            }
        }
        if (!fb) {
            // scatter directly into sorted-by-bin position (lists now L2-warm)
            #pragma unroll
            for (int q = 0; q < SPLIT; ++q) {
                const ull* gc = ws_cand + (size_t)(b * SPLIT + q) * LCAND;
                int nl = min((int)cntq[q], LCAND);
                for (int i = tid; i < nl; i += TPB) {
                    ull e = gc[i];
                    unsigned k = (unsigned)(e >> 32);
                    if (k >= Tkeyb) {
                        unsigned bin = (k - base) >> shift;
                        unsigned pos = atomicAdd(&hist[bin + 1], 1u);  // base S[bin+1]
                        cand2[pos] = e;
                    }
                }
            }
            __syncthreads();
            for (int e = bstar + tid; e < NB; e += TPB) {       // fix multi-elem bins
                int c = (int)cnts[e];
                if (c >= 2) {
                    int st = (int)hist[e + 1] - c;
                    for (int x = 1; x < c; ++x) {
                        ull key = cand2[st + x];
                        int y = x - 1;
                        while (y >= 0 && cand2[st + y] < key) { cand2[st + y + 1] = cand2[st + y]; --y; }
                        cand2[st + y + 1] = key;
                    }
                }
            }
            __syncthreads();
        }

        // ---------- slow path: full-row exact recompute (correctness net) ----------
        if (fb) {
            const float* __restrict__ row = logits + (size_t)b * V;
            float m = -1e30f, z = 0.0f;
            for (int i = tid; i < V; i += TPB) {
                float y = row[i] * invT;
                float nm = fmaxf(m, y);
                z = z * exp2f((m - nm) * L2E) + exp2f((y - nm) * L2E);
                m = nm;
            }
            sh_p[tid] = m; sh_c[tid] = z;
            __syncthreads();
            for (int d = TPB >> 1; d > 0; d >>= 1) {
                if (tid < d) {
                    float m1 = sh_p[tid], z1 = sh_c[tid];
                    float m2 = sh_p[tid + d], z2 = sh_c[tid + d];
                    float mm = fmaxf(m1, m2);
                    sh_c[tid] = z1 * exp2f((m1 - mm) * L2E) + z2 * exp2f((m2 - mm) * L2E);
                    sh_p[tid] = mm;
                }
                __syncthreads();
            }
            Y = sh_p[0]; Z = sh_c[0];
            __syncthreads();
            for (int i = tid; i < NB; i += TPB) hist[i] = 0;
            if (tid == 0) { sh_i1 = 0; sh_i2 = 0; sh_u1 = 0; }
            __syncthreads();
            for (int i = tid; i < V; i += TPB) atomicAdd(&hist[fkey(row[i]) >> 21], 1u);
            __syncthreads();
            suffix_scan_2048(hist, uscr, tid);
            for (int e = tid; e < NB; e += TPB) {
                unsigned Se = hist[e], Sn = (e < NB-1) ? hist[e+1] : 0u;
                if (Se >= Ku && Sn < Ku) { sh_i1 = e; sh_u1 = Sn; }
            }
            __syncthreads();
            int b1 = sh_i1;
            unsigned cab = sh_u1;
            for (int i = tid; i < NB; i += TPB) hist[i] = 0;
            __syncthreads();
            for (int i = tid; i < V; i += TPB) {
                unsigned k = fkey(row[i]);
                if ((int)(k >> 21) == b1) atomicAdd(&hist[(k >> 10) & (NB - 1)], 1u);
            }
            __syncthreads();
            suffix_scan_2048(hist, uscr, tid);
            for (int e = tid; e < NB; e += TPB) {
                unsigned Se = cab + hist[e];
                unsigned Sn = cab + ((e < NB-1) ? hist[e+1] : 0u);
                if (Se >= Ku && Sn < Ku) sh_i2 = e;
            }
            __syncthreads();
            unsigned Tkey = ((unsigned)b1 << 21) | ((unsigned)sh_i2 << 10);
            if (tid == 0) scnt = 0;
            __syncthreads();
            for (int i = tid; i < V; i += TPB) {
                unsigned k = fkey(row[i]);
                if (k >= Tkey) {
                    unsigned pos = atomicAdd(&scnt, 1u);
                    if (pos < CAND2) cand[pos] = packkv(k, (unsigned)i);
                }
            }
            __syncthreads();
            count = (scnt < (unsigned)CAND2) ? (int)scnt : CAND2;

            int n_sort = 1;
            while (n_sort < count) n_sort <<= 1;
            for (int i = tid; i < n_sort; i += TPB)
                if (i >= count) cand[i] = 0ull;
            __syncthreads();
            for (int kk = 2; kk <= n_sort; kk <<= 1) {
                for (int j = kk >> 1; j > 0; j >>= 1) {
                    for (int i = tid; i < n_sort; i += TPB) {
                        int ixj = i ^ j;
                        if (ixj > i) {
                            ull a = cand[i], c = cand[ixj];
                            bool up = (i & kk) == 0;
                            if (up ? (a < c) : (a > c)) { cand[i] = c; cand[ixj] = a; }
                        }
                    }
                    __syncthreads();
                }
            }
        }

        ull* srt = fb ? cand : cand2;
        int Kk = min(Korig, count);

        // ---------- probs for top-K prefix, shuffle prefix-sum ----------
        float pvp = 0.0f;
        if (tid < Kk) {
            unsigned k = (unsigned)(srt[tid] >> 32);
            pvp = exp2f((funkey(k) * invT - Y) * L2E) / Z;
        }
        float inc = pvp;
        #pragma unroll
        for (int d = 1; d < 64; d <<= 1) { float o = __shfl_up(inc, d); if (lane >= d) inc += o; }
        if (lane == 63) fws[w] = inc;
        __syncthreads();
        if (w == 0) {
            float v = (lane < 16) ? fws[lane] : 0.0f;
            float vi = v;
            #pragma unroll
            for (int d = 1; d < 16; d <<= 1) { float o = __shfl_up(vi, d); if (lane >= d) vi += o; }
            if (lane < 16) fws[16 + lane] = vi - v;
        }
        __syncthreads();
        float cum = inc + fws[16 + w];
        sh_p[tid] = pvp;
        sh_c[tid] = cum;
        if (tid == 0) sh_i1 = Kk;
        __syncthreads();

        // top-p (exclusive cumsum BEFORE masking, as reference)
        if (tid < Kk) {
            float excl = cum - pvp;
            if (excl > top_p) atomicMin(&sh_i1, tid);
        }
        __syncthreads();
        int n1 = sh_i1;
        float thr = sh_p[0] * min_p;
        if (tid == 0) sh_i2 = n1;
        __syncthreads();
        if (tid < n1 && sh_p[tid] < thr) atomicMin(&sh_i2, tid);
        __syncthreads();
        int nf = sh_i2;                         // >= 1
        float total = sh_c[nf - 1];

        // ---------- inverse-CDF sample ----------
        int pred = (tid < nf) && ((sh_c[tid] / total) < uval);
        int rank = __syncthreads_count(pred);
        if (rank > nf - 1) rank = nf - 1;
        if (rank < 0) rank = 0;
        if (tid == 0)
            out_tok[b] = (float)(~(unsigned)(srt[rank] & 0xFFFFFFFFull));

        // ---------- scatter survivors (out_probs zeroed in phase 1) ----------
        if (tid < nf) {
            unsigned idx = ~(unsigned)(srt[tid] & 0xFFFFFFFFull);
            out_probs[(size_t)b * V + idx] = sh_p[tid] / total;
        }
    }
}

extern "C" void kernel_launch(void* const* d_in, const int* in_sizes, int n_in,
                              void* d_out, int out_size, void* d_ws, size_t ws_size,
                              hipStream_t stream) {
    const float* logits = (const float*)d_in[0];
    const float* temps  = (const float*)d_in[1];
    const int*   top_ks = (const int*)d_in[2];
    const float* top_ps = (const float*)d_in[3];
    const float* min_ps = (const float*)d_in[4];
    const float* u      = (const float*)d_in[5];
    const int B = in_sizes[1];
    const int V = in_sizes[0] / B;
    float* out_tok   = (float*)d_out;
    float* out_probs = out_tok + B;

    int Vq = (((V + SPLIT - 1) / SPLIT) + 3) & ~3;   // quarter-row, float4-aligned

    char* ws = (char*)d_ws;
    size_t off = 0;
    auto take = [&](size_t bytes) { char* p = ws + off; off = (off + bytes + 255) & ~(size_t)255; return p; };
    float*    ws_meta = (float*)take((size_t)B * SPLIT * 2 * sizeof(float));
    unsigned* ws_cut  = (unsigned*)take((size_t)B * SPLIT * sizeof(unsigned));
    unsigned* ws_cnt  = (unsigned*)take((size_t)B * SPLIT * sizeof(unsigned));
    unsigned* ws_maxk = (unsigned*)take((size_t)B * SPLIT * sizeof(unsigned));
    unsigned* ws_done = (unsigned*)take((size_t)B * sizeof(unsigned));
    ull*      ws_cand = (ull*)take((size_t)B * SPLIT * LCAND * sizeof(ull));
    (void)ws_size;

    // zero the per-row completion counters (ws is poisoned between iterations)
    hipMemsetAsync(ws_done, 0, (size_t)B * sizeof(unsigned), stream);

    k_fused<<<dim3(SPLIT * B), dim3(TPB), 0, stream>>>(
        logits, temps, top_ks, top_ps, min_ps, u, out_tok, out_probs,
        ws_meta, ws_cut, ws_cnt, ws_maxk, ws_cand, ws_done, V, Vq);
}

// Round 5
// 148.694 us; speedup vs baseline: 1.5034x; 1.5034x over previous
//
#include <hip/hip_runtime.h>
#include <stdint.h>
#include <math.h>

#define TPB 1024
#define NB 2048           // histogram bins (k2)
#define SPLIT 4           // row split for scan blocks
#define LCAND 2560        // per-quarter-row candidate cap
#define CAND2 2048        // candidate cap in K2
#define PS 4096           // presample count per block (== 4*TPB for vector path)
#define L2E 1.44269504088896f

typedef float vfloat4 __attribute__((ext_vector_type(4)));
typedef unsigned long long ull;

// monotonic float -> uint key (ascending key == ascending float)
__device__ __forceinline__ unsigned fkey(float f) {
    unsigned u = __float_as_uint(f);
    return (u & 0x80000000u) ? ~u : (u | 0x80000000u);
}
__device__ __forceinline__ float funkey(unsigned k) {
    unsigned u = (k & 0x80000000u) ? (k ^ 0x80000000u) : ~k;
    return __uint_as_float(u);
}
__device__ __forceinline__ ull packkv(unsigned k, unsigned idx) {
    return ((ull)k << 32) | (ull)(~idx);    // ~idx: desc key sort => asc idx ties
}

// Phi^{-1}(1-p) for 1e-7 <= p <= 0.45 (Hastings / A&S 26.2.23, |err|<4.5e-4)
__device__ __forceinline__ float inv_norm_tail(float p) {
    float t = sqrtf(-2.0f * logf(p));
    float num = 2.515517f + t * (0.802853f + t * 0.010328f);
    float den = 1.0f + t * (1.432788f + t * (0.189269f + t * 0.001308f));
    return t - num / den;
}

// in-place suffix sum of h[0..NB). Caller must barrier before; ends barriered.
__device__ __forceinline__ void suffix_scan_2048(unsigned* h, unsigned* wscr, int tid)
{
    const int lane = tid & 63, w = tid >> 6;
    const int i0 = 2047 - 2 * tid;
    const int i1 = 2046 - 2 * tid;
    unsigned a = h[i0], b = h[i1];
    unsigned s = a + b;
    unsigned inc = s;
    #pragma unroll
    for (int d = 1; d < 64; d <<= 1) { unsigned o = __shfl_up(inc, d); if (lane >= d) inc += o; }
    if (lane == 63) wscr[w] = inc;
    __syncthreads();
    if (w == 0) {
        unsigned v = (lane < 16) ? wscr[lane] : 0u;
        unsigned vi = v;
        #pragma unroll
        for (int d = 1; d < 16; d <<= 1) { unsigned o = __shfl_up(vi, d); if (lane >= d) vi += o; }
        if (lane < 16) wscr[16 + lane] = vi - v;
    }
    __syncthreads();
    unsigned off = wscr[16 + w] + (inc - s);
    h[i0] = off + a;
    h[i1] = off + a + b;
    __syncthreads();
}

// ============================ K1 ============================
// grid = SPLIT*B. Moment-based cut: presample (1 float4/thread, kept in regs)
// -> mean/var/max reduce (2 barriers, no histogram/scan) -> Gaussian-quantile
// cut targeting C = 2K+256 row survivors -> zero epilogue FIRST (NT stores
// drain while reads stream) -> batched read pass: 4 loads in flight, 4 indep
// Z accums, candidate gather, full-quarter max tracking (for k2).
// Any cut misestimate is caught by k2's exactness guards -> exact fallback.
// NOTE (R4 lesson): do NOT fuse k1/k2 into one kernel with device fences —
// per-XCD L2 is non-coherent, and the required threadfence release/acquire
// pairs (L2 writeback/invalidate per block) collapse streaming BW to ~8%.
// The kernel boundary is the cheap coherence point.
__global__ __launch_bounds__(TPB)
void k1_scan(const float* __restrict__ logits,
             const float* __restrict__ temps,
             const int* __restrict__ top_ks,
             float* __restrict__ out_probs,
             float* __restrict__ ws_meta,   // [slot][2] {Cy, z}
             unsigned* __restrict__ ws_cut, // [slot]
             unsigned* __restrict__ ws_cnt, // [slot] raw count (overflow visible)
             unsigned* __restrict__ ws_max, // [slot] fkey(full-quarter max)
             ull* __restrict__ ws_cand,     // [slot][LCAND]
             int V, int Vq)
{
    const int sblk = blockIdx.x;
    const int b = sblk / SPLIT, s = sblk % SPLIT;
    const int tid = threadIdx.x, lane = tid & 63, w = tid >> 6;
    const int start = s * Vq;
    const int len = min(Vq, V - start);
    const int slot = sblk;
    const float invT = 1.0f / temps[b];
    int K = top_ks[b]; K = max(K, 1); K = min(K, 1024);

    __shared__ float fred[52];     // [0:16) sum, [16:32) sumsq, [32:48) max, 48/49 results
    __shared__ unsigned uscr[32];
    __shared__ unsigned cnt;

    if (len <= 0) {
        if (tid == 0) {
            ws_meta[2*slot] = -1e30f; ws_meta[2*slot+1] = 0.0f;
            ws_cut[slot] = 0xFFFFFFFFu; ws_cnt[slot] = 0u; ws_max[slot] = 0u;
        }
        return;
    }

    if (tid == 0) cnt = 0;

    const float* __restrict__ row = logits + (size_t)b * V + start;
    const vfloat4* __restrict__ row4 = (const vfloat4*)row;
    float* __restrict__ orow = out_probs + (size_t)b * V + start;
    vfloat4* __restrict__ orow4 = (vfloat4*)orow;
    const vfloat4 z4 = (vfloat4)0.0f;
    const int L4 = len >> 2;
    const bool vec = (len >= 4 * TPB);        // presample fits 1 float4/thread
    const int nps = vec ? (4 * TPB) : min(len, PS);

    // ---- presample: sum/sumsq/max; vector path keeps values in regs ----
    float sm = 0.0f, sq = 0.0f, m0 = -1e30f;
    vfloat4 pv = z4;
    if (vec) {
        pv = row4[tid];
        __builtin_nontemporal_store(z4, &orow4[tid]);   // zero presample region now
        sm = (pv[0] + pv[1]) + (pv[2] + pv[3]);
        sq = (pv[0]*pv[0] + pv[1]*pv[1]) + (pv[2]*pv[2] + pv[3]*pv[3]);
        m0 = fmaxf(fmaxf(pv[0], pv[1]), fmaxf(pv[2], pv[3]));
    } else {
        for (int i = tid; i < nps; i += TPB) {
            float lv = row[i];
            sm += lv; sq += lv * lv;
            m0 = fmaxf(m0, lv);
        }
    }
    #pragma unroll
    for (int d = 32; d > 0; d >>= 1) {
        sm += __shfl_down(sm, d);
        sq += __shfl_down(sq, d);
        m0 = fmaxf(m0, __shfl_down(m0, d));
    }
    if (lane == 0) { fred[w] = sm; fred[16 + w] = sq; fred[32 + w] = m0; }
    __syncthreads();
    if (tid == 0) {
        float S = 0.0f, Q = 0.0f, M = -1e30f;
        for (int j = 0; j < 16; ++j) {
            S += fred[j]; Q += fred[16 + j]; M = fmaxf(M, fred[32 + j]);
        }
        float n  = (float)nps;
        float mu = S / n;
        float var = fmaxf(Q / n - mu * mu, 0.0f);
        float sg = sqrtf(var);
        float Cf = 2.0f * (float)K + 256.0f;          // target row survivors
        float p  = Cf / (float)V;
        p = fminf(fmaxf(p, 1e-7f), 0.45f);
        fred[48] = mu + sg * inv_norm_tail(p);        // cutval
        fred[49] = M;                                 // exp base (sample max)
    }
    __syncthreads();
    const float cutval = fred[48];
    const float m0max  = fred[49];
    const unsigned cutkey = fkey(cutval);

    // ---- zero epilogue FIRST (nt stores drain while reads stream) ----
    if (vec) {
        for (int i = TPB + tid; i < L4; i += TPB) __builtin_nontemporal_store(z4, &orow4[i]);
        for (int i = (L4 << 2) + tid; i < len; i += TPB) __builtin_nontemporal_store(0.0f, &orow[i]);
    } else {
        for (int i = tid; i < L4; i += TPB) __builtin_nontemporal_store(z4, &orow4[i]);
        for (int i = (L4 << 2) + tid; i < len; i += TPB) __builtin_nontemporal_store(0.0f, &orow[i]);
    }

    const float ca = invT * L2E;
    const float cb = -m0max * invT * L2E;
    ull* gc = ws_cand + (size_t)slot * LCAND;

    float z0 = 0.0f, z1 = 0.0f, z2 = 0.0f, z3 = 0.0f;
    float mA = m0, mB = -1e30f, mC = -1e30f, mD = -1e30f;

    #define E4(v) (exp2f(fmaf((v)[0], ca, cb)) + exp2f(fmaf((v)[1], ca, cb)) \
                 + exp2f(fmaf((v)[2], ca, cb)) + exp2f(fmaf((v)[3], ca, cb)))
    #define M4(v) fmaxf(fmaxf((v)[0], (v)[1]), fmaxf((v)[2], (v)[3]))
    #define GATHER(v, ii) do {                                                  \
        bool c0 = (v)[0] >= cutval, c1 = (v)[1] >= cutval,                      \
             c2 = (v)[2] >= cutval, c3 = (v)[3] >= cutval;                      \
        if (c0 | c1 | c2 | c3) {                                                \
            int nh = (int)c0 + (int)c1 + (int)c2 + (int)c3;                     \
            unsigned base = atomicAdd(&cnt, (unsigned)nh);                      \
            unsigned bi = (unsigned)(start + ((ii) << 2));                      \
            if (c0) { if (base < LCAND) gc[base] = packkv(fkey((v)[0]), bi+0); base++; } \
            if (c1) { if (base < LCAND) gc[base] = packkv(fkey((v)[1]), bi+1); base++; } \
            if (c2) { if (base < LCAND) gc[base] = packkv(fkey((v)[2]), bi+2); base++; } \
            if (c3) { if (base < LCAND) gc[base] = packkv(fkey((v)[3]), bi+3); base++; } \
        }                                                                       \
    } while (0)

    // ---- main read pass: 4 plain loads in flight, 4 indep accumulators ----
    if (vec) {
        int i = TPB + tid;
        for (; i + 3 * TPB < L4; i += 4 * TPB) {
            vfloat4 va = row4[i];
            vfloat4 vb = row4[i + TPB];
            vfloat4 vc = row4[i + 2 * TPB];
            vfloat4 vd = row4[i + 3 * TPB];
            z0 += E4(va); z1 += E4(vb); z2 += E4(vc); z3 += E4(vd);
            mA = fmaxf(mA, M4(va)); mB = fmaxf(mB, M4(vb));
            mC = fmaxf(mC, M4(vc)); mD = fmaxf(mD, M4(vd));
            GATHER(va, i); GATHER(vb, i + TPB); GATHER(vc, i + 2 * TPB); GATHER(vd, i + 3 * TPB);
        }
        for (; i < L4; i += TPB) {
            vfloat4 v = row4[i];
            z0 += E4(v);
            mA = fmaxf(mA, M4(v));
            GATHER(v, i);
        }
        for (int j = (L4 << 2) + tid; j < len; j += TPB) {
            float lv = row[j];
            z0 += exp2f(fmaf(lv, ca, cb));
            mA = fmaxf(mA, lv);
            if (lv >= cutval) {
                unsigned base = atomicAdd(&cnt, 1u);
                if (base < LCAND) gc[base] = packkv(fkey(lv), (unsigned)(start + j));
            }
        }
        // presample values (already loaded, already zero-stored)
        z0 += E4(pv);
        GATHER(pv, tid);
    } else {
        int i = tid;
        for (; i + 3 * TPB < L4; i += 4 * TPB) {
            vfloat4 va = row4[i];
            vfloat4 vb = row4[i + TPB];
            vfloat4 vc = row4[i + 2 * TPB];
            vfloat4 vd = row4[i + 3 * TPB];
            z0 += E4(va); z1 += E4(vb); z2 += E4(vc); z3 += E4(vd);
            mA = fmaxf(mA, M4(va)); mB = fmaxf(mB, M4(vb));
            mC = fmaxf(mC, M4(vc)); mD = fmaxf(mD, M4(vd));
            GATHER(va, i); GATHER(vb, i + TPB); GATHER(vc, i + 2 * TPB); GATHER(vd, i + 3 * TPB);
        }
        for (; i < L4; i += TPB) {
            vfloat4 v = row4[i];
            z0 += E4(v);
            mA = fmaxf(mA, M4(v));
            GATHER(v, i);
        }
        for (int j = (L4 << 2) + tid; j < len; j += TPB) {
            float lv = row[j];
            z0 += exp2f(fmaf(lv, ca, cb));
            mA = fmaxf(mA, lv);
            if (lv >= cutval) {
                unsigned base = atomicAdd(&cnt, 1u);
                if (base < LCAND) gc[base] = packkv(fkey(lv), (unsigned)(start + j));
            }
        }
    }
    #undef E4
    #undef M4
    #undef GATHER

    float z = (z0 + z1) + (z2 + z3);
    unsigned rk = fkey(fmaxf(fmaxf(mA, mB), fmaxf(mC, mD)));
    __syncthreads();   // protect fred/uscr reuse
    #pragma unroll
    for (int d = 32; d > 0; d >>= 1) {
        z += __shfl_down(z, d);
        rk = max(rk, __shfl_down(rk, d));
    }
    if (lane == 0) { fred[w] = z; uscr[w] = rk; }
    __syncthreads();
    if (tid == 0) {
        float zz = 0.0f;
        unsigned mk = 0u;
        for (int j = 0; j < 16; ++j) { zz += fred[j]; mk = max(mk, uscr[j]); }
        ws_meta[2*slot + 0] = m0max * invT;   // Cy
        ws_meta[2*slot + 1] = zz;             // sum 2^((x-m0max)*invT*L2E)
        ws_cut[slot] = cutkey;
        ws_cnt[slot] = cnt;
        ws_max[slot] = mk;
    }
}

// ============================ K2 ============================
// grid = B. Single-pass adaptive threshold + scatter-sort; full-row fallback.
// maxkey comes from K1 (no pass over candidate lists needed for it).
__global__ __launch_bounds__(TPB)
void k2_sample(const float* __restrict__ logits,
               const float* __restrict__ temps,
               const int* __restrict__ top_ks,
               const float* __restrict__ top_ps,
               const float* __restrict__ min_ps,
               const float* __restrict__ uvec,
               const float* __restrict__ ws_meta,
               const unsigned* __restrict__ ws_cut,
               const unsigned* __restrict__ ws_cnt,
               const unsigned* __restrict__ ws_max,
               const ull* __restrict__ ws_cand,
               float* __restrict__ out_tok,
               float* __restrict__ out_probs,
               int V)
{
    const int b = blockIdx.x;
    const int tid = threadIdx.x, lane = tid & 63, w = tid >> 6;
    const float invT = 1.0f / temps[b];
    int Korig = top_ks[b]; Korig = max(Korig, 1); Korig = min(Korig, 1024);
    const unsigned Ku = (unsigned)Korig;
    const float top_p = top_ps[b], min_p = min_ps[b], uval = uvec[b];

    // LDS carve
    __shared__ __align__(16) char smem[53504];
    ull*            cand  = (ull*)(smem);                       // [2048] (fb path)
    ull*            cand2 = (ull*)(smem + 16384);               // [2048] sorted dest
    unsigned*       hist  = (unsigned*)(smem + 32768);          // [2049]
    unsigned short* cnts  = (unsigned short*)(smem + 41216);    // [2048]
    float*          sh_p  = (float*)(smem + 45312);             // [1024]
    float*          sh_c  = (float*)(smem + 49408);             // [1024]
    __shared__ unsigned uscr[32];
    __shared__ float fws[32];
    __shared__ unsigned scnt;
    __shared__ int sh_i1, sh_i2;
    __shared__ unsigned sh_u1;

    // ---- combine per-block meta ----
    float Cy[SPLIT], zq[SPLIT];
    unsigned cutq[SPLIT], cntq[SPLIT], mxq[SPLIT];
    #pragma unroll
    for (int q = 0; q < SPLIT; ++q) {
        int sl = b * SPLIT + q;
        Cy[q] = ws_meta[2*sl]; zq[q] = ws_meta[2*sl+1];
        cutq[q] = ws_cut[sl]; cntq[q] = ws_cnt[sl]; mxq[q] = ws_max[sl];
    }
    float Y = -1e30f;
    #pragma unroll
    for (int q = 0; q < SPLIT; ++q) if (cntq[q] > 0u) Y = fmaxf(Y, Cy[q]);
    float Z = 0.0f;
    #pragma unroll
    for (int q = 0; q < SPLIT; ++q)
        if (cntq[q] > 0u && zq[q] > 0.0f) Z += zq[q] * exp2f((Cy[q] - Y) * L2E);

    bool fb = false;
    unsigned cutmax = 0, mincut = 0xFFFFFFFFu;
    #pragma unroll
    for (int q = 0; q < SPLIT; ++q) {
        if (cntq[q] > (unsigned)LCAND) fb = true;          // list truncated
        if (cntq[q] > 0u) {
            if (!isfinite(zq[q])) fb = true;               // Z overflow -> exact path
            cutmax = max(cutmax, cutq[q]);
            mincut = min(mincut, cutq[q]);
        }
    }
    if (mincut == 0xFFFFFFFFu || !isfinite(Z) || Z <= 0.0f) fb = true;

    unsigned Tkeyb = 0;
    int count = 0, bstar = 0, shift = 0;
    unsigned base = mincut;

    // ---------- fast path: one adaptive histogram over candidate lists ----------
    if (!fb) {
        for (int i = tid; i <= NB; i += TPB) hist[i] = 0;   // incl hist[2048]
        if (tid == 0) sh_i1 = -1;
        // maxkey from K1's full-quarter max (true row max is in some list, or fb)
        unsigned maxkey = 0;
        #pragma unroll
        for (int q = 0; q < SPLIT; ++q)
            if (cntq[q] > 0u) maxkey = max(maxkey, mxq[q]);
        const unsigned range = maxkey - base;
        while ((range >> shift) > (unsigned)(NB - 1)) shift++;
        __syncthreads();

        // histogram pass (first and only cold touch of the lists)
        #pragma unroll
        for (int q = 0; q < SPLIT; ++q) {
            const ull* gc = ws_cand + (size_t)(b * SPLIT + q) * LCAND;
            int nl = min((int)cntq[q], LCAND);
            for (int i = tid; i < nl; i += TPB)
                atomicAdd(&hist[((unsigned)(gc[i] >> 32) - base) >> shift], 1u);
        }
        __syncthreads();
        unsigned fat = 0;
        for (int i = tid; i < NB; i += TPB) {
            unsigned h = hist[i];
            cnts[i] = (unsigned short)h;
            fat = max(fat, h);
        }
        #pragma unroll
        for (int d = 32; d > 0; d >>= 1) fat = max(fat, __shfl_down(fat, d));
        if (lane == 0) uscr[w] = fat;
        __syncthreads();
        if (tid == 0) {
            unsigned m2 = 0;
            for (int j = 0; j < 16; ++j) m2 = max(m2, uscr[j]);
            uscr[16] = m2;
        }
        __syncthreads();
        if (uscr[16] > 64u) fb = true;                      // fat bin -> fallback
    }
    if (!fb) {
        suffix_scan_2048(hist, uscr, tid);
        for (int e = tid; e < NB; e += TPB) {
            unsigned Se = hist[e], Sn = (e < NB - 1) ? hist[e + 1] : 0u;
            if (Se >= Ku && Sn < Ku) { sh_i1 = e; sh_u1 = Se; }
        }
        __syncthreads();
        if (sh_i1 < 0) fb = true;
        else {
            bstar = sh_i1;
            count = (int)sh_u1;
            Tkeyb = base + ((unsigned)bstar << shift);
            if (Tkeyb < cutmax || count > CAND2) fb = true; // exactness guards
        }
    }
    if (!fb) {
        // scatter directly into sorted-by-bin position (lists now L2-warm)
        #pragma unroll
        for (int q = 0; q < SPLIT; ++q) {
            const ull* gc = ws_cand + (size_t)(b * SPLIT + q) * LCAND;
            int nl = min((int)cntq[q], LCAND);
            for (int i = tid; i < nl; i += TPB) {
                ull e = gc[i];
                unsigned k = (unsigned)(e >> 32);
                if (k >= Tkeyb) {
                    unsigned bin = (k - base) >> shift;
                    unsigned pos = atomicAdd(&hist[bin + 1], 1u);  // base S[bin+1]
                    cand2[pos] = e;
                }
            }
        }
        __syncthreads();
        for (int e = bstar + tid; e < NB; e += TPB) {       // fix multi-elem bins
            int c = (int)cnts[e];
            if (c >= 2) {
                int st = (int)hist[e + 1] - c;
                for (int x = 1; x < c; ++x) {
                    ull key = cand2[st + x];
                    int y = x - 1;
                    while (y >= 0 && cand2[st + y] < key) { cand2[st + y + 1] = cand2[st + y]; --y; }
                    cand2[st + y + 1] = key;
                }
            }
        }
        __syncthreads();
    }

    // ---------- slow path: full-row exact recompute (correctness net) ----------
    if (fb) {
        const float* __restrict__ row = logits + (size_t)b * V;
        float m = -1e30f, z = 0.0f;
        for (int i = tid; i < V; i += TPB) {
            float y = row[i] * invT;
            float nm = fmaxf(m, y);
            z = z * exp2f((m - nm) * L2E) + exp2f((y - nm) * L2E);
            m = nm;
        }
        sh_p[tid] = m; sh_c[tid] = z;
        __syncthreads();
        for (int d = TPB >> 1; d > 0; d >>= 1) {
            if (tid < d) {
                float m1 = sh_p[tid], z1 = sh_c[tid];
                float m2 = sh_p[tid + d], z2 = sh_c[tid + d];
                float mm = fmaxf(m1, m2);
                sh_c[tid] = z1 * exp2f((m1 - mm) * L2E) + z2 * exp2f((m2 - mm) * L2E);
                sh_p[tid] = mm;
            }
            __syncthreads();
        }
        Y = sh_p[0]; Z = sh_c[0];
        __syncthreads();
        for (int i = tid; i < NB; i += TPB) hist[i] = 0;
        if (tid == 0) { sh_i1 = 0; sh_i2 = 0; sh_u1 = 0; }
        __syncthreads();
        for (int i = tid; i < V; i += TPB) atomicAdd(&hist[fkey(row[i]) >> 21], 1u);
        __syncthreads();
        suffix_scan_2048(hist, uscr, tid);
        for (int e = tid; e < NB; e += TPB) {
            unsigned Se = hist[e], Sn = (e < NB-1) ? hist[e+1] : 0u;
            if (Se >= Ku && Sn < Ku) { sh_i1 = e; sh_u1 = Sn; }
        }
        __syncthreads();
        int b1 = sh_i1;
        unsigned cab = sh_u1;
        for (int i = tid; i < NB; i += TPB) hist[i] = 0;
        __syncthreads();
        for (int i = tid; i < V; i += TPB) {
            unsigned k = fkey(row[i]);
            if ((int)(k >> 21) == b1) atomicAdd(&hist[(k >> 10) & (NB - 1)], 1u);
        }
        __syncthreads();
        suffix_scan_2048(hist, uscr, tid);
        for (int e = tid; e < NB; e += TPB) {
            unsigned Se = cab + hist[e];
            unsigned Sn = cab + ((e < NB-1) ? hist[e+1] : 0u);
            if (Se >= Ku && Sn < Ku) sh_i2 = e;
        }
        __syncthreads();
        unsigned Tkey = ((unsigned)b1 << 21) | ((unsigned)sh_i2 << 10);
        if (tid == 0) scnt = 0;
        __syncthreads();
        for (int i = tid; i < V; i += TPB) {
            unsigned k = fkey(row[i]);
            if (k >= Tkey) {
                unsigned pos = atomicAdd(&scnt, 1u);
                if (pos < CAND2) cand[pos] = packkv(k, (unsigned)i);
            }
        }
        __syncthreads();
        count = (scnt < (unsigned)CAND2) ? (int)scnt : CAND2;

        int n_sort = 1;
        while (n_sort < count) n_sort <<= 1;
        for (int i = tid; i < n_sort; i += TPB)
            if (i >= count) cand[i] = 0ull;
        __syncthreads();
        for (int kk = 2; kk <= n_sort; kk <<= 1) {
            for (int j = kk >> 1; j > 0; j >>= 1) {
                for (int i = tid; i < n_sort; i += TPB) {
                    int ixj = i ^ j;
                    if (ixj > i) {
                        ull a = cand[i], c = cand[ixj];
                        bool up = (i & kk) == 0;
                        if (up ? (a < c) : (a > c)) { cand[i] = c; cand[ixj] = a; }
                    }
                }
                __syncthreads();
            }
        }
    }

    ull* srt = fb ? cand : cand2;
    int K = min(Korig, count);

    // ---------- probs for top-K prefix, shuffle prefix-sum ----------
    float pv = 0.0f;
    if (tid < K) {
        unsigned k = (unsigned)(srt[tid] >> 32);
        pv = exp2f((funkey(k) * invT - Y) * L2E) / Z;
    }
    float inc = pv;
    #pragma unroll
    for (int d = 1; d < 64; d <<= 1) { float o = __shfl_up(inc, d); if (lane >= d) inc += o; }
    if (lane == 63) fws[w] = inc;
    __syncthreads();
    if (w == 0) {
        float v = (lane < 16) ? fws[lane] : 0.0f;
        float vi = v;
        #pragma unroll
        for (int d = 1; d < 16; d <<= 1) { float o = __shfl_up(vi, d); if (lane >= d) vi += o; }
        if (lane < 16) fws[16 + lane] = vi - v;
    }
    __syncthreads();
    float cum = inc + fws[16 + w];
    sh_p[tid] = pv;
    sh_c[tid] = cum;
    if (tid == 0) sh_i1 = K;
    __syncthreads();

    // top-p (exclusive cumsum BEFORE masking, as reference)
    if (tid < K) {
        float excl = cum - pv;
        if (excl > top_p) atomicMin(&sh_i1, tid);
    }
    __syncthreads();
    int n1 = sh_i1;
    float thr = sh_p[0] * min_p;
    if (tid == 0) sh_i2 = n1;
    __syncthreads();
    if (tid < n1 && sh_p[tid] < thr) atomicMin(&sh_i2, tid);
    __syncthreads();
    int nf = sh_i2;                         // >= 1
    float total = sh_c[nf - 1];

    // ---------- inverse-CDF sample ----------
    int pred = (tid < nf) && ((sh_c[tid] / total) < uval);
    int rank = __syncthreads_count(pred);
    if (rank > nf - 1) rank = nf - 1;
    if (rank < 0) rank = 0;
    if (tid == 0)
        out_tok[b] = (float)(~(unsigned)(srt[rank] & 0xFFFFFFFFull));

    // ---------- scatter survivors (out_probs zeroed by K1) ----------
    if (tid < nf) {
        unsigned idx = ~(unsigned)(srt[tid] & 0xFFFFFFFFull);
        out_probs[(size_t)b * V + idx] = sh_p[tid] / total;
    }
}

extern "C" void kernel_launch(void* const* d_in, const int* in_sizes, int n_in,
                              void* d_out, int out_size, void* d_ws, size_t ws_size,
                              hipStream_t stream) {
    const float* logits = (const float*)d_in[0];
    const float* temps  = (const float*)d_in[1];
    const int*   top_ks = (const int*)d_in[2];
    const float* top_ps = (const float*)d_in[3];
    const float* min_ps = (const float*)d_in[4];
    const float* u      = (const float*)d_in[5];
    const int B = in_sizes[1];
    const int V = in_sizes[0] / B;
    float* out_tok   = (float*)d_out;
    float* out_probs = out_tok + B;

    int Vq = (((V + SPLIT - 1) / SPLIT) + 3) & ~3;   // quarter-row, float4-aligned

    char* ws = (char*)d_ws;
    size_t off = 0;
    auto take = [&](size_t bytes) { char* p = ws + off; off = (off + bytes + 255) & ~(size_t)255; return p; };
    float*    ws_meta = (float*)take((size_t)B * SPLIT * 2 * sizeof(float));
    unsigned* ws_cut  = (unsigned*)take((size_t)B * SPLIT * sizeof(unsigned));
    unsigned* ws_cnt  = (unsigned*)take((size_t)B * SPLIT * sizeof(unsigned));
    unsigned* ws_maxk = (unsigned*)take((size_t)B * SPLIT * sizeof(unsigned));
    ull*      ws_cand = (ull*)take((size_t)B * SPLIT * LCAND * sizeof(ull));
    (void)ws_size;

    k1_scan<<<dim3(SPLIT * B), dim3(TPB), 0, stream>>>(
        logits, temps, top_ks, out_probs, ws_meta, ws_cut, ws_cnt, ws_maxk, ws_cand, V, Vq);
    k2_sample<<<dim3(B), dim3(TPB), 0, stream>>>(
        logits, temps, top_ks, top_ps, min_ps, u, ws_meta, ws_cut, ws_cnt, ws_maxk, ws_cand,
        out_tok, out_probs, V);
}